// Round 14
// baseline (330.465 us; speedup 1.0000x reference)
//
#include <hip/hip_runtime.h>

#define NF 128
#define NGRAPHS 64
#define NCLS 10
#define NPARTS 256         // dst partitions, 512 nodes each (n <= 131072)
#define PART_SHIFT 9
#define PART_NODES 512
#define PART_CAP 9216      // mean 6250 + ~37 sigma slack
#define SPLIT_TILE 4096
#define MAX_TILES 512      // ne <= 2M edges
#define AS_STRIDE 136      // bf16 elems per LDS A-row (128 + 8 pad)
#define SRC_BITS 17        // src < 2^17 (n <= 131072); record = dlocal<<17 | src

typedef __attribute__((ext_vector_type(8))) short bf16x8;          // MFMA frag
typedef __attribute__((ext_vector_type(4))) float f32x4;
typedef __attribute__((ext_vector_type(8))) unsigned short u16x8;  // 16B row chunk

__device__ __forceinline__ float bf2f(unsigned short u) {
    union { unsigned int i; float f; } v; v.i = ((unsigned int)u) << 16; return v.f;
}
__device__ __forceinline__ unsigned short f2bf(float f) {
    union { float f; unsigned int i; } v; v.f = f;
    unsigned int lsb = (v.i >> 16) & 1;
    v.i += 0x7fffu + lsb;                 // RNE
    return (unsigned short)(v.i >> 16);
}

// ---------------------------------------------------------------------------
// Fused prep + split, fully DETERMINISTIC (no global atomics, no memset dep).
// Prep (grid-stride): cast feat->bf16, transpose+cast W1/W2, zero sums.
// Split: per 4096-edge tile, registers stage (dst,src); LDS histogram+scan
// orders records by partition; flush = contiguous coalesced copy; per-tile
// cnts/hbase tables let build reassemble without any cross-block atomics.
// ---------------------------------------------------------------------------
__global__ __launch_bounds__(256) void split_prep_kernel(
    const int* __restrict__ src, const int* __restrict__ dst,
    unsigned int* __restrict__ records, int* __restrict__ cnts,
    int* __restrict__ hbase_g,
    const float* __restrict__ feat, unsigned short* __restrict__ featbf,
    const float* __restrict__ W1, const float* __restrict__ W2,
    unsigned short* __restrict__ Wt1, unsigned short* __restrict__ Wt2,
    float* __restrict__ sums, int ne, int nv4) {
    __shared__ unsigned int stage[SPLIT_TILE];  // 16 KB
    __shared__ int hcnt[NPARTS];
    __shared__ int hscan[NPARTS];
    __shared__ int hcur[NPARTS];
    int t = threadIdx.x;
    int gtid = blockIdx.x * 256 + t;
    int nthreads = gridDim.x * 256;

    // ---- prep (grid-stride over all blocks) ----
    for (int i = gtid; i < nv4; i += nthreads) {
        float4 v = ((const float4*)feat)[i];
        ushort4 o;
        o.x = f2bf(v.x); o.y = f2bf(v.y); o.z = f2bf(v.z); o.w = f2bf(v.w);
        ((ushort4*)featbf)[i] = o;
    }
    for (int i = gtid; i < 2 * NF * NF; i += nthreads) {
        const float* W = (i < NF * NF) ? W1 : W2;
        unsigned short* Wt = (i < NF * NF) ? Wt1 : Wt2;
        int id = i & (NF * NF - 1);
        int f = id >> 7;
        int k = id & 127;
        Wt[f * NF + k] = f2bf(W[k * NF + f]);
    }
    for (int i = gtid; i < NGRAPHS * NF; i += nthreads) sums[i] = 0.f;

    // ---- split ----
    int tile0 = blockIdx.x * SPLIT_TILE;
    int cnt = min(SPLIT_TILE, ne - tile0);
    if (cnt <= 0) return;
    hcnt[t] = 0;
    __syncthreads();
    // pass 1: load (dst,src) into registers + histogram
    int dv[16], sv[16];
#pragma unroll
    for (int k2 = 0; k2 < 16; ++k2) {
        int i = k2 * 256 + t;
        if (i < cnt) {
            dv[k2] = dst[tile0 + i];
            sv[k2] = src[tile0 + i];
            atomicAdd(&hcnt[dv[k2] >> PART_SHIFT], 1);
        }
    }
    __syncthreads();
    // inclusive Hillis-Steele scan of 256 counters
    hscan[t] = hcnt[t];
    __syncthreads();
    for (int off = 1; off < NPARTS; off <<= 1) {
        int v = (t >= off) ? hscan[t - off] : 0;
        __syncthreads();
        hscan[t] += v;
        __syncthreads();
    }
    hcur[t] = hscan[t] - hcnt[t];
    // publish per-tile tables (deterministic handoff to build)
    cnts[(size_t)blockIdx.x * NPARTS + t] = hcnt[t];
    hbase_g[(size_t)blockIdx.x * NPARTS + t] = hscan[t] - hcnt[t];
    __syncthreads();
    // pass 2: place packed records from registers, grouped by partition
#pragma unroll
    for (int k2 = 0; k2 < 16; ++k2) {
        int i = k2 * 256 + t;
        if (i < cnt) {
            int d = dv[k2];
            int pos = atomicAdd(&hcur[d >> PART_SHIFT], 1);
            stage[pos] = (((unsigned int)(d & (PART_NODES - 1))) << SRC_BITS)
                         | (unsigned int)sv[k2];
        }
    }
    __syncthreads();
    // flush: the stage is already partition-ordered -> straight coalesced copy
    for (int i = t; i < cnt; i += 256) records[tile0 + i] = stage[i];
}

// ---------------------------------------------------------------------------
// Per-partition CSR build (one block per 512-node partition). Reassembles
// its records from the per-tile slices (LDS tile-prefix + binary search),
// LDS degree hist + scan -> offs/degs; eid written at fixed base p*PART_CAP
// (no global scan, no atomics).
// ---------------------------------------------------------------------------
__global__ __launch_bounds__(256) void build_kernel(
    const unsigned int* __restrict__ records, const int* __restrict__ cnts,
    const int* __restrict__ hbase_g, int* __restrict__ offs,
    int* __restrict__ degs, int* __restrict__ eid, int n, int ntiles) {
    __shared__ int deg[PART_NODES];         // 2 KB; becomes cursor after scan
    __shared__ int pref[MAX_TILES + 1];     // 2 KB tile prefix
    __shared__ int hb[MAX_TILES];           // 2 KB
    __shared__ unsigned int rc[PART_CAP];   // 36 KB record cache
    __shared__ int wsum[4];
    __shared__ int Ltot;
    int t = threadIdx.x;
    int p = blockIdx.x;
    int lo = p << PART_SHIFT;
    int nn = min(n - lo, PART_NODES);
    if (nn <= 0) return;

    deg[t] = 0;
    deg[t + 256] = 0;

    // load column p of cnts/hbase (2 tiles/thread) and scan over tiles
    int i0 = 2 * t, i1 = 2 * t + 1;
    int c0 = 0, c1 = 0;
    if (i0 < ntiles) { c0 = cnts[(size_t)i0 * NPARTS + p]; hb[i0] = hbase_g[(size_t)i0 * NPARTS + p]; }
    if (i1 < ntiles) { c1 = cnts[(size_t)i1 * NPARTS + p]; hb[i1] = hbase_g[(size_t)i1 * NPARTS + p]; }
    int tsum = c0 + c1;
    int lane = t & 63, w = t >> 6;
    int sc = tsum;
    for (int off = 1; off < 64; off <<= 1) {
        int u = __shfl_up(sc, off, 64);
        if (lane >= off) sc += u;
    }
    if (lane == 63) wsum[w] = sc;
    __syncthreads();
    if (t == 0) {
        int a = 0;
        for (int k = 0; k < 4; ++k) { int v = wsum[k]; wsum[k] = a; a += v; }
        Ltot = a;
    }
    __syncthreads();
    int run = sc - tsum + wsum[w];
    if (i0 < ntiles) pref[i0] = run;
    run += c0;
    if (i1 < ntiles) pref[i1] = run;
    if (t == 0) pref[ntiles] = Ltot;
    __syncthreads();

    int L = min(Ltot, PART_CAP);

    // gather records from tile slices + histogram
    for (int i = t; i < L; i += 256) {
        int lo2 = 0, hi2 = ntiles;
        while (lo2 + 1 < hi2) {
            int mid = (lo2 + hi2) >> 1;
            if (pref[mid] <= i) lo2 = mid; else hi2 = mid;
        }
        unsigned int r = records[(size_t)lo2 * SPLIT_TILE + hb[lo2] + (i - pref[lo2])];
        rc[i] = r;
        atomicAdd(&deg[r >> SRC_BITS], 1);
    }
    __syncthreads();

    // block exclusive scan over deg[0..512) (2 elems/thread)
    int v0 = deg[2 * t];
    int v1 = deg[2 * t + 1];
    int tsum2 = v0 + v1;
    int sc2 = tsum2;
    for (int off = 1; off < 64; off <<= 1) {
        int u = __shfl_up(sc2, off, 64);
        if (lane >= off) sc2 += u;
    }
    if (lane == 63) wsum[w] = sc2;
    __syncthreads();
    if (t == 0) {
        int a = 0;
        for (int k = 0; k < 4; ++k) { int v = wsum[k]; wsum[k] = a; a += v; }
    }
    __syncthreads();
    int run2 = sc2 - tsum2 + wsum[w];
    int base_g = p * PART_CAP;
    deg[2 * t] = run2;
    if (2 * t < nn) { offs[lo + 2 * t] = base_g + run2; degs[lo + 2 * t] = v0; }
    run2 += v0;
    deg[2 * t + 1] = run2;
    if (2 * t + 1 < nn) { offs[lo + 2 * t + 1] = base_g + run2; degs[lo + 2 * t + 1] = v1; }
    __syncthreads();

    // fill eid from the LDS cache
    for (int i = t; i < L; i += 256) {
        unsigned int r = rc[i];
        int pos = atomicAdd(&deg[r >> SRC_BITS], 1);
        eid[base_g + pos] = (int)(r & ((1u << SRC_BITS) - 1));
    }
}

// ---------------------------------------------------------------------------
// Fused gather + MFMA GEMM (layer 1): unchanged structure (gather at its
// per-XCD compulsory-miss ceiling); end = beg + degs[node].
// ---------------------------------------------------------------------------
__global__ __launch_bounds__(256) void gather_gemm1(
    const unsigned short* __restrict__ x, const int* __restrict__ offs,
    const int* __restrict__ degs, const int* __restrict__ eid,
    const unsigned short* __restrict__ Wt,
    const float* __restrict__ bias, unsigned short* __restrict__ out, int n) {
    __shared__ unsigned short As[16 * AS_STRIDE];
    int wave = threadIdx.x >> 6;
    int lane = threadIdx.x & 63;
    int q = lane >> 4;        // quarter 0..3
    int c = lane & 15;        // 16B chunk / m-index
    int node_base = blockIdx.x * 16;

    for (int i = 0; i < 4; ++i) {
        int row = wave * 4 + i;
        int node = node_base + row;
        float acc[8] = {0.f, 0.f, 0.f, 0.f, 0.f, 0.f, 0.f, 0.f};
        if (node < n) {
            int beg = offs[node];
            int end = beg + degs[node];
            int j = beg + q;
            for (; j + 4 < end; j += 8) {
                int s0 = eid[j];
                int s1 = eid[j + 4];
                u16x8 v0 = ((const u16x8*)(x + (size_t)s0 * NF))[c];
                u16x8 v1 = ((const u16x8*)(x + (size_t)s1 * NF))[c];
#pragma unroll
                for (int r = 0; r < 8; ++r) acc[r] += bf2f(v0[r]) + bf2f(v1[r]);
            }
            if (j < end) {
                int s0 = eid[j];
                u16x8 v0 = ((const u16x8*)(x + (size_t)s0 * NF))[c];
#pragma unroll
                for (int r = 0; r < 8; ++r) acc[r] += bf2f(v0[r]);
            }
        }
#pragma unroll
        for (int r = 0; r < 8; ++r) acc[r] += __shfl_xor(acc[r], 16, 64);
#pragma unroll
        for (int r = 0; r < 8; ++r) acc[r] += __shfl_xor(acc[r], 32, 64);
        if (q == 0) {
            u16x8 o;
#pragma unroll
            for (int r = 0; r < 8; ++r) o[r] = f2bf(acc[r]);
            *(u16x8*)(&As[row * AS_STRIDE + c * 8]) = o;
        }
    }
    __syncthreads();

    int m16 = c;
    int n0 = wave * 32;
    const unsigned short* b0r = Wt + (size_t)(n0 + m16) * NF + q * 8;
    const unsigned short* b1r = b0r + 16 * NF;
    f32x4 acc0 = {0.f, 0.f, 0.f, 0.f};
    f32x4 acc1 = {0.f, 0.f, 0.f, 0.f};
#pragma unroll
    for (int kk = 0; kk < 4; ++kk) {
        bf16x8 a  = *(const bf16x8*)(&As[m16 * AS_STRIDE + kk * 32 + q * 8]);
        bf16x8 b0 = *(const bf16x8*)(b0r + kk * 32);
        bf16x8 b1 = *(const bf16x8*)(b1r + kk * 32);
        acc0 = __builtin_amdgcn_mfma_f32_16x16x32_bf16(a, b0, acc0, 0, 0, 0);
        acc1 = __builtin_amdgcn_mfma_f32_16x16x32_bf16(a, b1, acc1, 0, 0, 0);
    }
    float bias0 = bias[n0 + m16];
    float bias1 = bias[n0 + 16 + m16];
#pragma unroll
    for (int r = 0; r < 4; ++r) {
        int node = node_base + q * 4 + r;
        if (node >= n) break;
        unsigned short* o = out + (size_t)node * NF;
        o[n0 + m16]      = f2bf(fmaxf(acc0[r] + bias0, 0.f));
        o[n0 + 16 + m16] = f2bf(fmaxf(acc1[r] + bias1, 0.f));
    }
}

// ---------------------------------------------------------------------------
// Fused gather + MFMA GEMM (layer 2) + pool epilogue. No device fences
// (r12 post-mortem: per-block __threadfence = 8x regression).
// ---------------------------------------------------------------------------
__global__ __launch_bounds__(256) void gather_gemm2_pool(
    const unsigned short* __restrict__ x, const int* __restrict__ offs,
    const int* __restrict__ degs, const int* __restrict__ eid,
    const unsigned short* __restrict__ Wt,
    const float* __restrict__ bias, const int* __restrict__ gid,
    float* __restrict__ sums, int n) {
    __shared__ unsigned short As[16 * AS_STRIDE];
    __shared__ float hblk[16][NF];
    int wave = threadIdx.x >> 6;
    int lane = threadIdx.x & 63;
    int q = lane >> 4;
    int c = lane & 15;
    int node_base = blockIdx.x * 16;

    for (int i = 0; i < 4; ++i) {
        int row = wave * 4 + i;
        int node = node_base + row;
        float acc[8] = {0.f, 0.f, 0.f, 0.f, 0.f, 0.f, 0.f, 0.f};
        if (node < n) {
            int beg = offs[node];
            int end = beg + degs[node];
            int j = beg + q;
            for (; j + 4 < end; j += 8) {
                int s0 = eid[j];
                int s1 = eid[j + 4];
                u16x8 v0 = ((const u16x8*)(x + (size_t)s0 * NF))[c];
                u16x8 v1 = ((const u16x8*)(x + (size_t)s1 * NF))[c];
#pragma unroll
                for (int r = 0; r < 8; ++r) acc[r] += bf2f(v0[r]) + bf2f(v1[r]);
            }
            if (j < end) {
                int s0 = eid[j];
                u16x8 v0 = ((const u16x8*)(x + (size_t)s0 * NF))[c];
#pragma unroll
                for (int r = 0; r < 8; ++r) acc[r] += bf2f(v0[r]);
            }
        }
#pragma unroll
        for (int r = 0; r < 8; ++r) acc[r] += __shfl_xor(acc[r], 16, 64);
#pragma unroll
        for (int r = 0; r < 8; ++r) acc[r] += __shfl_xor(acc[r], 32, 64);
        if (q == 0) {
            u16x8 o;
#pragma unroll
            for (int r = 0; r < 8; ++r) o[r] = f2bf(acc[r]);
            *(u16x8*)(&As[row * AS_STRIDE + c * 8]) = o;
        }
    }
    __syncthreads();

    int m16 = c;
    int n0 = wave * 32;
    const unsigned short* b0r = Wt + (size_t)(n0 + m16) * NF + q * 8;
    const unsigned short* b1r = b0r + 16 * NF;
    f32x4 acc0 = {0.f, 0.f, 0.f, 0.f};
    f32x4 acc1 = {0.f, 0.f, 0.f, 0.f};
#pragma unroll
    for (int kk = 0; kk < 4; ++kk) {
        bf16x8 a  = *(const bf16x8*)(&As[m16 * AS_STRIDE + kk * 32 + q * 8]);
        bf16x8 b0 = *(const bf16x8*)(b0r + kk * 32);
        bf16x8 b1 = *(const bf16x8*)(b1r + kk * 32);
        acc0 = __builtin_amdgcn_mfma_f32_16x16x32_bf16(a, b0, acc0, 0, 0, 0);
        acc1 = __builtin_amdgcn_mfma_f32_16x16x32_bf16(a, b1, acc1, 0, 0, 0);
    }
    float bias0 = bias[n0 + m16];
    float bias1 = bias[n0 + 16 + m16];
#pragma unroll
    for (int r = 0; r < 4; ++r) {
        int row = q * 4 + r;
        hblk[row][n0 + m16]      = fmaxf(acc0[r] + bias0, 0.f);
        hblk[row][n0 + 16 + m16] = fmaxf(acc1[r] + bias1, 0.f);
    }
    __syncthreads();

    int t = threadIdx.x;
    if (t < NF) {
        float acc = 0.f;
        int cur = -1;
        int lim = min(16, n - node_base);
        for (int i = 0; i < lim; ++i) {
            int g = gid[node_base + i];
            if (g != cur) {
                if (cur >= 0) atomicAdd(&sums[cur * NF + t], acc);
                acc = 0.f;
                cur = g;
            }
            acc += bf2f(f2bf(hblk[i][t]));    // keep bf16 rounding of h2 path
        }
        if (cur >= 0) atomicAdd(&sums[cur * NF + t], acc);
    }
}

__device__ __forceinline__ int lower_bound_i(const int* a, int n, int key) {
    int lo = 0, hi = n;
    while (lo < hi) {
        int mid = (lo + hi) >> 1;
        if (a[mid] < key) lo = mid + 1; else hi = mid;
    }
    return lo;
}

__global__ __launch_bounds__(64) void final_kernel(
    const float* __restrict__ sums, const int* __restrict__ gid, int n,
    const float* __restrict__ Wp, const float* __restrict__ bp,
    float* __restrict__ out) {
    __shared__ int range[2];
    int g = blockIdx.x;
    int c = threadIdx.x;
    if (c == 0) range[0] = lower_bound_i(gid, n, g);
    if (c == 1) range[1] = lower_bound_i(gid, n, g + 1);
    __syncthreads();
    if (c >= NCLS) return;
    float cnt = fmaxf((float)(range[1] - range[0]), 1.0f);
    float inv = 1.0f / cnt;
    float acc = bp[c];
#pragma unroll 8
    for (int k = 0; k < NF; ++k) {
        acc += sums[g * NF + k] * inv * Wp[k * NCLS + c];
    }
    out[g * NCLS + c] = acc;
}

extern "C" void kernel_launch(void* const* d_in, const int* in_sizes, int n_in,
                              void* d_out, int out_size, void* d_ws, size_t ws_size,
                              hipStream_t stream) {
    const float* feat = (const float*)d_in[0];
    const float* W1   = (const float*)d_in[1];
    const float* b1   = (const float*)d_in[2];
    const float* W2   = (const float*)d_in[3];
    const float* b2   = (const float*)d_in[4];
    const float* Wp   = (const float*)d_in[5];
    const float* bp   = (const float*)d_in[6];
    const int*   src  = (const int*)d_in[7];
    const int*   dst  = (const int*)d_in[8];
    const int*   gid  = (const int*)d_in[9];

    int ne = in_sizes[7];
    int n  = in_sizes[9];

    int ntiles = (ne + SPLIT_TILE - 1) / SPLIT_TILE;   // <= MAX_TILES

    // Workspace (16B-aligned segments):
    unsigned short* featbf = (unsigned short*)d_ws;                  // n*128 u16
    unsigned short* h1     = featbf + (size_t)n * NF;                // n*128 u16
    unsigned int* records = (unsigned int*)(h1 + (size_t)n * NF);    // ne u32 (tile-grouped)
    int* eid      = (int*)(records + ne);                            // NPARTS*PART_CAP
    float* sums   = (float*)(eid + (size_t)NPARTS * PART_CAP);       // 64*128
    int* cnts     = (int*)(sums + NGRAPHS * NF);                     // ntiles*NPARTS
    int* hbase_g  = cnts + (size_t)ntiles * NPARTS;                  // ntiles*NPARTS
    unsigned short* Wt1 = (unsigned short*)(hbase_g + (size_t)ntiles * NPARTS);
    unsigned short* Wt2 = Wt1 + NF * NF;                             // 128*128
    int* offs     = (int*)(Wt2 + NF * NF);                           // n
    int* degs     = offs + n;                                        // n

    int nv4 = n * NF / 4;
    int buildblocks = (n + PART_NODES - 1) >> PART_SHIFT;
    int ggblocks = (n + 15) / 16;

    split_prep_kernel<<<ntiles, 256, 0, stream>>>(
        src, dst, records, cnts, hbase_g, feat, featbf, W1, W2, Wt1, Wt2,
        sums, ne, nv4);
    build_kernel<<<buildblocks, 256, 0, stream>>>(
        records, cnts, hbase_g, offs, degs, eid, n, ntiles);

    gather_gemm1<<<ggblocks, 256, 0, stream>>>(featbf, offs, degs, eid, Wt1, b1, h1, n);
    gather_gemm2_pool<<<ggblocks, 256, 0, stream>>>(h1, offs, degs, eid, Wt2, b2, gid, sums, n);
    final_kernel<<<NGRAPHS, 64, 0, stream>>>(sums, gid, n, Wp, bp, (float*)d_out);
}

// Round 15
// 316.036 us; speedup vs baseline: 1.0457x; 1.0457x over previous
//
#include <hip/hip_runtime.h>

#define NF 128
#define NGRAPHS 64
#define NCLS 10
#define NPARTS 256         // dst partitions, 512 nodes each (n <= 131072)
#define PART_SHIFT 9
#define PART_NODES 512
#define PART_CAP 9216      // mean 6250 + ~37 sigma slack
#define SPLIT_TILE 4096
#define AS_STRIDE 136      // bf16 elems per LDS A-row (128 + 8 pad)
#define SRC_BITS 17        // src < 2^17 (n <= 131072); record = dlocal<<17 | src

typedef __attribute__((ext_vector_type(8))) short bf16x8;          // MFMA frag
typedef __attribute__((ext_vector_type(4))) float f32x4;
typedef __attribute__((ext_vector_type(8))) unsigned short u16x8;  // 16B row chunk

__device__ __forceinline__ float bf2f(unsigned short u) {
    union { unsigned int i; float f; } v; v.i = ((unsigned int)u) << 16; return v.f;
}
__device__ __forceinline__ unsigned short f2bf(float f) {
    union { float f; unsigned int i; } v; v.f = f;
    unsigned int lsb = (v.i >> 16) & 1;
    v.i += 0x7fffu + lsb;                 // RNE
    return (unsigned short)(v.i >> 16);
}

// ---------------------------------------------------------------------------
// Fused prep + split (register-staged). r13 configuration: gcur atomic
// reservation + scattered per-partition flush (r14's deterministic handoff
// regressed: scattered tile-slice re-reads cost more than the atomics).
// gcur is zeroed by a prior hipMemsetAsync.
// ---------------------------------------------------------------------------
__global__ __launch_bounds__(256) void split_prep_kernel(
    const int* __restrict__ src, const int* __restrict__ dst,
    unsigned int* __restrict__ records, int* __restrict__ gcur,
    const float* __restrict__ feat, unsigned short* __restrict__ featbf,
    const float* __restrict__ W1, const float* __restrict__ W2,
    unsigned short* __restrict__ Wt1, unsigned short* __restrict__ Wt2,
    float* __restrict__ sums, int ne, int nv4) {
    __shared__ unsigned int stage[SPLIT_TILE];  // 16 KB
    __shared__ int hcnt[NPARTS];
    __shared__ int hscan[NPARTS];
    __shared__ int hcur[NPARTS];
    __shared__ int hg[NPARTS];
    int t = threadIdx.x;
    int gtid = blockIdx.x * 256 + t;
    int nthreads = gridDim.x * 256;

    // ---- prep (grid-stride over all blocks) ----
    for (int i = gtid; i < nv4; i += nthreads) {
        float4 v = ((const float4*)feat)[i];
        ushort4 o;
        o.x = f2bf(v.x); o.y = f2bf(v.y); o.z = f2bf(v.z); o.w = f2bf(v.w);
        ((ushort4*)featbf)[i] = o;
    }
    for (int i = gtid; i < 2 * NF * NF; i += nthreads) {
        const float* W = (i < NF * NF) ? W1 : W2;
        unsigned short* Wt = (i < NF * NF) ? Wt1 : Wt2;
        int id = i & (NF * NF - 1);
        int f = id >> 7;
        int k = id & 127;
        Wt[f * NF + k] = f2bf(W[k * NF + f]);
    }
    for (int i = gtid; i < NGRAPHS * NF; i += nthreads) sums[i] = 0.f;

    // ---- split ----
    int tile0 = blockIdx.x * SPLIT_TILE;
    int cnt = min(SPLIT_TILE, ne - tile0);
    if (cnt <= 0) return;
    hcnt[t] = 0;
    __syncthreads();
    // pass 1: load (dst,src) into registers + histogram
    int dv[16], sv[16];
#pragma unroll
    for (int k2 = 0; k2 < 16; ++k2) {
        int i = k2 * 256 + t;
        if (i < cnt) {
            dv[k2] = dst[tile0 + i];
            sv[k2] = src[tile0 + i];
            atomicAdd(&hcnt[dv[k2] >> PART_SHIFT], 1);
        }
    }
    __syncthreads();
    // inclusive Hillis-Steele scan of 256 counters
    hscan[t] = hcnt[t];
    __syncthreads();
    for (int off = 1; off < NPARTS; off <<= 1) {
        int v = (t >= off) ? hscan[t - off] : 0;
        __syncthreads();
        hscan[t] += v;
        __syncthreads();
    }
    hcur[t] = hscan[t] - hcnt[t];
    hg[t] = hcnt[t] ? atomicAdd(&gcur[t], hcnt[t]) : 0;
    __syncthreads();
    // pass 2: place packed records from registers
#pragma unroll
    for (int k2 = 0; k2 < 16; ++k2) {
        int i = k2 * 256 + t;
        if (i < cnt) {
            int d = dv[k2];
            int pos = atomicAdd(&hcur[d >> PART_SHIFT], 1);
            stage[pos] = (((unsigned int)(d & (PART_NODES - 1))) << SRC_BITS)
                         | (unsigned int)sv[k2];
        }
    }
    __syncthreads();
    // flush: quarter-wave (16 lanes) per partition, 16 partitions concurrent
    int grp = t >> 4;
    int lt = t & 15;
    for (int p = grp; p < NPARTS; p += 16) {
        int c = hcnt[p];
        if (c == 0) continue;
        int b = hscan[p] - c;
        int g = hg[p];
        if (g + c > PART_CAP) c = max(0, PART_CAP - g);   // never in practice
        unsigned int* outp = records + (size_t)p * PART_CAP + g;
        for (int i = lt; i < c; i += 16) outp[i] = stage[b + i];
    }
}

// ---------------------------------------------------------------------------
// Per-partition CSR build with LDS record cache (r13 configuration).
// ---------------------------------------------------------------------------
__global__ __launch_bounds__(256) void build_kernel(
    const unsigned int* __restrict__ records, const int* __restrict__ gcur,
    int* __restrict__ offs, int* __restrict__ eid, int n) {
    __shared__ int deg[PART_NODES];       // 2 KB; becomes cursor after scan
    __shared__ int ps[NPARTS];            // 1 KB
    __shared__ int wsum[4];
    __shared__ unsigned int rc[PART_CAP]; // 36 KB record cache
    int t = threadIdx.x;
    int p = blockIdx.x;

    // partition-base scan (inclusive)
    ps[t] = min(gcur[t], PART_CAP);
    __syncthreads();
    for (int off = 1; off < NPARTS; off <<= 1) {
        int v = (t >= off) ? ps[t - off] : 0;
        __syncthreads();
        ps[t] += v;
        __syncthreads();
    }
    int L = min(gcur[p], PART_CAP);
    int base_g = ps[p] - L;
    if (p == 0 && t == 0) offs[n] = ps[NPARTS - 1];

    int lo = p << PART_SHIFT;
    int nn = min(n - lo, PART_NODES);
    if (nn <= 0) return;

    deg[t] = 0;
    deg[t + 256] = 0;
    __syncthreads();

    const unsigned int* rp = records + (size_t)p * PART_CAP;
    for (int i = t; i < L; i += 256) {
        unsigned int r = rp[i];
        rc[i] = r;
        atomicAdd(&deg[r >> SRC_BITS], 1);
    }
    __syncthreads();

    // block exclusive scan over deg[0..512) (2 elems/thread)
    int v0 = deg[2 * t];
    int v1 = deg[2 * t + 1];
    int tsum = v0 + v1;
    int lane = t & 63, w = t >> 6;
    int sc = tsum;
    for (int off = 1; off < 64; off <<= 1) {
        int u = __shfl_up(sc, off, 64);
        if (lane >= off) sc += u;
    }
    if (lane == 63) wsum[w] = sc;
    __syncthreads();
    if (t == 0) {
        int a = 0;
        for (int k = 0; k < 4; ++k) { int v = wsum[k]; wsum[k] = a; a += v; }
    }
    __syncthreads();
    int run = sc - tsum + wsum[w];
    deg[2 * t] = run;
    if (2 * t < nn) offs[lo + 2 * t] = base_g + run;
    run += v0;
    deg[2 * t + 1] = run;
    if (2 * t + 1 < nn) offs[lo + 2 * t + 1] = base_g + run;
    __syncthreads();

    // fill eid from the LDS cache
    for (int i = t; i < L; i += 256) {
        unsigned int r = rc[i];
        int pos = atomicAdd(&deg[r >> SRC_BITS], 1);
        eid[base_g + pos] = (int)(r & ((1u << SRC_BITS) - 1));
    }
}

// ---------------------------------------------------------------------------
// Fused gather + MFMA GEMM (layer 1): at the random-256B gather ceiling
// (FETCH = 8 XCDs x ~86.5K unique rows x 256 B compulsory misses).
// ---------------------------------------------------------------------------
__global__ __launch_bounds__(256) void gather_gemm1(
    const unsigned short* __restrict__ x, const int* __restrict__ offs,
    const int* __restrict__ eid, const unsigned short* __restrict__ Wt,
    const float* __restrict__ bias, unsigned short* __restrict__ out, int n) {
    __shared__ unsigned short As[16 * AS_STRIDE];
    int wave = threadIdx.x >> 6;
    int lane = threadIdx.x & 63;
    int q = lane >> 4;        // quarter 0..3
    int c = lane & 15;        // 16B chunk / m-index
    int node_base = blockIdx.x * 16;

    for (int i = 0; i < 4; ++i) {
        int row = wave * 4 + i;
        int node = node_base + row;
        float acc[8] = {0.f, 0.f, 0.f, 0.f, 0.f, 0.f, 0.f, 0.f};
        if (node < n) {
            int beg = offs[node];
            int end = offs[node + 1];
            int j = beg + q;
            for (; j + 4 < end; j += 8) {
                int s0 = eid[j];
                int s1 = eid[j + 4];
                u16x8 v0 = ((const u16x8*)(x + (size_t)s0 * NF))[c];
                u16x8 v1 = ((const u16x8*)(x + (size_t)s1 * NF))[c];
#pragma unroll
                for (int r = 0; r < 8; ++r) acc[r] += bf2f(v0[r]) + bf2f(v1[r]);
            }
            if (j < end) {
                int s0 = eid[j];
                u16x8 v0 = ((const u16x8*)(x + (size_t)s0 * NF))[c];
#pragma unroll
                for (int r = 0; r < 8; ++r) acc[r] += bf2f(v0[r]);
            }
        }
#pragma unroll
        for (int r = 0; r < 8; ++r) acc[r] += __shfl_xor(acc[r], 16, 64);
#pragma unroll
        for (int r = 0; r < 8; ++r) acc[r] += __shfl_xor(acc[r], 32, 64);
        if (q == 0) {
            u16x8 o;
#pragma unroll
            for (int r = 0; r < 8; ++r) o[r] = f2bf(acc[r]);
            *(u16x8*)(&As[row * AS_STRIDE + c * 8]) = o;
        }
    }
    __syncthreads();

    int m16 = c;
    int n0 = wave * 32;
    const unsigned short* b0r = Wt + (size_t)(n0 + m16) * NF + q * 8;
    const unsigned short* b1r = b0r + 16 * NF;
    f32x4 acc0 = {0.f, 0.f, 0.f, 0.f};
    f32x4 acc1 = {0.f, 0.f, 0.f, 0.f};
#pragma unroll
    for (int kk = 0; kk < 4; ++kk) {
        bf16x8 a  = *(const bf16x8*)(&As[m16 * AS_STRIDE + kk * 32 + q * 8]);
        bf16x8 b0 = *(const bf16x8*)(b0r + kk * 32);
        bf16x8 b1 = *(const bf16x8*)(b1r + kk * 32);
        acc0 = __builtin_amdgcn_mfma_f32_16x16x32_bf16(a, b0, acc0, 0, 0, 0);
        acc1 = __builtin_amdgcn_mfma_f32_16x16x32_bf16(a, b1, acc1, 0, 0, 0);
    }
    float bias0 = bias[n0 + m16];
    float bias1 = bias[n0 + 16 + m16];
#pragma unroll
    for (int r = 0; r < 4; ++r) {
        int node = node_base + q * 4 + r;
        if (node >= n) break;
        unsigned short* o = out + (size_t)node * NF;
        o[n0 + m16]      = f2bf(fmaxf(acc0[r] + bias0, 0.f));
        o[n0 + 16 + m16] = f2bf(fmaxf(acc1[r] + bias1, 0.f));
    }
}

// ---------------------------------------------------------------------------
// Fused gather + MFMA GEMM (layer 2) + pool epilogue. No device fences
// (r12 post-mortem: per-block __threadfence = 8x regression).
// ---------------------------------------------------------------------------
__global__ __launch_bounds__(256) void gather_gemm2_pool(
    const unsigned short* __restrict__ x, const int* __restrict__ offs,
    const int* __restrict__ eid, const unsigned short* __restrict__ Wt,
    const float* __restrict__ bias, const int* __restrict__ gid,
    float* __restrict__ sums, int n) {
    __shared__ unsigned short As[16 * AS_STRIDE];
    __shared__ float hblk[16][NF];
    int wave = threadIdx.x >> 6;
    int lane = threadIdx.x & 63;
    int q = lane >> 4;
    int c = lane & 15;
    int node_base = blockIdx.x * 16;

    for (int i = 0; i < 4; ++i) {
        int row = wave * 4 + i;
        int node = node_base + row;
        float acc[8] = {0.f, 0.f, 0.f, 0.f, 0.f, 0.f, 0.f, 0.f};
        if (node < n) {
            int beg = offs[node];
            int end = offs[node + 1];
            int j = beg + q;
            for (; j + 4 < end; j += 8) {
                int s0 = eid[j];
                int s1 = eid[j + 4];
                u16x8 v0 = ((const u16x8*)(x + (size_t)s0 * NF))[c];
                u16x8 v1 = ((const u16x8*)(x + (size_t)s1 * NF))[c];
#pragma unroll
                for (int r = 0; r < 8; ++r) acc[r] += bf2f(v0[r]) + bf2f(v1[r]);
            }
            if (j < end) {
                int s0 = eid[j];
                u16x8 v0 = ((const u16x8*)(x + (size_t)s0 * NF))[c];
#pragma unroll
                for (int r = 0; r < 8; ++r) acc[r] += bf2f(v0[r]);
            }
        }
#pragma unroll
        for (int r = 0; r < 8; ++r) acc[r] += __shfl_xor(acc[r], 16, 64);
#pragma unroll
        for (int r = 0; r < 8; ++r) acc[r] += __shfl_xor(acc[r], 32, 64);
        if (q == 0) {
            u16x8 o;
#pragma unroll
            for (int r = 0; r < 8; ++r) o[r] = f2bf(acc[r]);
            *(u16x8*)(&As[row * AS_STRIDE + c * 8]) = o;
        }
    }
    __syncthreads();

    int m16 = c;
    int n0 = wave * 32;
    const unsigned short* b0r = Wt + (size_t)(n0 + m16) * NF + q * 8;
    const unsigned short* b1r = b0r + 16 * NF;
    f32x4 acc0 = {0.f, 0.f, 0.f, 0.f};
    f32x4 acc1 = {0.f, 0.f, 0.f, 0.f};
#pragma unroll
    for (int kk = 0; kk < 4; ++kk) {
        bf16x8 a  = *(const bf16x8*)(&As[m16 * AS_STRIDE + kk * 32 + q * 8]);
        bf16x8 b0 = *(const bf16x8*)(b0r + kk * 32);
        bf16x8 b1 = *(const bf16x8*)(b1r + kk * 32);
        acc0 = __builtin_amdgcn_mfma_f32_16x16x32_bf16(a, b0, acc0, 0, 0, 0);
        acc1 = __builtin_amdgcn_mfma_f32_16x16x32_bf16(a, b1, acc1, 0, 0, 0);
    }
    float bias0 = bias[n0 + m16];
    float bias1 = bias[n0 + 16 + m16];
#pragma unroll
    for (int r = 0; r < 4; ++r) {
        int row = q * 4 + r;
        hblk[row][n0 + m16]      = fmaxf(acc0[r] + bias0, 0.f);
        hblk[row][n0 + 16 + m16] = fmaxf(acc1[r] + bias1, 0.f);
    }
    __syncthreads();

    int t = threadIdx.x;
    if (t < NF) {
        float acc = 0.f;
        int cur = -1;
        int lim = min(16, n - node_base);
        for (int i = 0; i < lim; ++i) {
            int g = gid[node_base + i];
            if (g != cur) {
                if (cur >= 0) atomicAdd(&sums[cur * NF + t], acc);
                acc = 0.f;
                cur = g;
            }
            acc += bf2f(f2bf(hblk[i][t]));    // keep bf16 rounding of h2 path
        }
        if (cur >= 0) atomicAdd(&sums[cur * NF + t], acc);
    }
}

__device__ __forceinline__ int lower_bound_i(const int* a, int n, int key) {
    int lo = 0, hi = n;
    while (lo < hi) {
        int mid = (lo + hi) >> 1;
        if (a[mid] < key) lo = mid + 1; else hi = mid;
    }
    return lo;
}

__global__ __launch_bounds__(64) void final_kernel(
    const float* __restrict__ sums, const int* __restrict__ gid, int n,
    const float* __restrict__ Wp, const float* __restrict__ bp,
    float* __restrict__ out) {
    __shared__ int range[2];
    int g = blockIdx.x;
    int c = threadIdx.x;
    if (c == 0) range[0] = lower_bound_i(gid, n, g);
    if (c == 1) range[1] = lower_bound_i(gid, n, g + 1);
    __syncthreads();
    if (c >= NCLS) return;
    float cnt = fmaxf((float)(range[1] - range[0]), 1.0f);
    float inv = 1.0f / cnt;
    float acc = bp[c];
#pragma unroll 8
    for (int k = 0; k < NF; ++k) {
        acc += sums[g * NF + k] * inv * Wp[k * NCLS + c];
    }
    out[g * NCLS + c] = acc;
}

extern "C" void kernel_launch(void* const* d_in, const int* in_sizes, int n_in,
                              void* d_out, int out_size, void* d_ws, size_t ws_size,
                              hipStream_t stream) {
    const float* feat = (const float*)d_in[0];
    const float* W1   = (const float*)d_in[1];
    const float* b1   = (const float*)d_in[2];
    const float* W2   = (const float*)d_in[3];
    const float* b2   = (const float*)d_in[4];
    const float* Wp   = (const float*)d_in[5];
    const float* bp   = (const float*)d_in[6];
    const int*   src  = (const int*)d_in[7];
    const int*   dst  = (const int*)d_in[8];
    const int*   gid  = (const int*)d_in[9];

    int ne = in_sizes[7];
    int n  = in_sizes[9];

    // Workspace (16B-aligned segments):
    unsigned short* featbf = (unsigned short*)d_ws;                  // n*128 u16
    unsigned short* h1     = featbf + (size_t)n * NF;                // n*128 u16
    unsigned int* records = (unsigned int*)(h1 + (size_t)n * NF);    // 256*PART_CAP u32
    int* eid      = (int*)(records + (size_t)NPARTS * PART_CAP);     // ne
    float* sums   = (float*)(eid + ne);                              // 64*128
    int* gcur     = (int*)(sums + NGRAPHS * NF);                     // 256
    unsigned short* Wt1 = (unsigned short*)(gcur + NPARTS);          // 128*128
    unsigned short* Wt2 = Wt1 + NF * NF;                             // 128*128
    int* offs     = (int*)(Wt2 + NF * NF);                           // n+1

    int nv4 = n * NF / 4;
    int splitblocks = (ne + SPLIT_TILE - 1) / SPLIT_TILE;
    int buildblocks = (n + PART_NODES - 1) >> PART_SHIFT;
    int ggblocks = (n + 15) / 16;

    hipMemsetAsync(gcur, 0, NPARTS * sizeof(int), stream);
    split_prep_kernel<<<splitblocks, 256, 0, stream>>>(
        src, dst, records, gcur, feat, featbf, W1, W2, Wt1, Wt2, sums, ne, nv4);
    build_kernel<<<buildblocks, 256, 0, stream>>>(records, gcur, offs, eid, n);

    gather_gemm1<<<ggblocks, 256, 0, stream>>>(featbf, offs, eid, Wt1, b1, h1, n);
    gather_gemm2_pool<<<ggblocks, 256, 0, stream>>>(h1, offs, eid, Wt2, b2, gid, sums, n);
    final_kernel<<<NGRAPHS, 64, 0, stream>>>(sums, gid, n, Wp, bp, (float*)d_out);
}

// Round 17
// 314.639 us; speedup vs baseline: 1.0503x; 1.0044x over previous
//
#include <hip/hip_runtime.h>

#define NF 128
#define NGRAPHS 64
#define NCLS 10
#define NPARTS 256         // dst partitions, 512 nodes each (n <= 131072)
#define PART_SHIFT 9
#define PART_NODES 512
#define PART_CAP 9216      // mean 6250 + ~37 sigma slack
#define SPLIT_TILE 4096
#define AS_STRIDE 136      // bf16 elems per LDS A-row (128 + 8 pad)
#define SRC_BITS 17        // src < 2^17 (n <= 131072); record = dlocal<<17 | src

typedef __attribute__((ext_vector_type(8))) short bf16x8;          // MFMA frag
typedef __attribute__((ext_vector_type(4))) float f32x4;
typedef __attribute__((ext_vector_type(8))) unsigned short u16x8;  // 16B row chunk

__device__ __forceinline__ float bf2f(unsigned short u) {
    union { unsigned int i; float f; } v; v.i = ((unsigned int)u) << 16; return v.f;
}
__device__ __forceinline__ unsigned short f2bf(float f) {
    union { float f; unsigned int i; } v; v.f = f;
    unsigned int lsb = (v.i >> 16) & 1;
    v.i += 0x7fffu + lsb;                 // RNE
    return (unsigned short)(v.i >> 16);
}

// ---------------------------------------------------------------------------
// Fused prep + split (register-staged). r13/r15 configuration: gcur atomic
// reservation + scattered per-partition flush. Cooperative fusion of this
// pipeline (r16) breaks graph capture — kernel boundaries are the only legal
// grid-wide sync in this harness. gcur zeroed by prior hipMemsetAsync.
// ---------------------------------------------------------------------------
__global__ __launch_bounds__(256) void split_prep_kernel(
    const int* __restrict__ src, const int* __restrict__ dst,
    unsigned int* __restrict__ records, int* __restrict__ gcur,
    const float* __restrict__ feat, unsigned short* __restrict__ featbf,
    const float* __restrict__ W1, const float* __restrict__ W2,
    unsigned short* __restrict__ Wt1, unsigned short* __restrict__ Wt2,
    float* __restrict__ sums, int ne, int nv4) {
    __shared__ unsigned int stage[SPLIT_TILE];  // 16 KB
    __shared__ int hcnt[NPARTS];
    __shared__ int hscan[NPARTS];
    __shared__ int hcur[NPARTS];
    __shared__ int hg[NPARTS];
    int t = threadIdx.x;
    int gtid = blockIdx.x * 256 + t;
    int nthreads = gridDim.x * 256;

    // ---- prep (grid-stride over all blocks) ----
    for (int i = gtid; i < nv4; i += nthreads) {
        float4 v = ((const float4*)feat)[i];
        ushort4 o;
        o.x = f2bf(v.x); o.y = f2bf(v.y); o.z = f2bf(v.z); o.w = f2bf(v.w);
        ((ushort4*)featbf)[i] = o;
    }
    for (int i = gtid; i < 2 * NF * NF; i += nthreads) {
        const float* W = (i < NF * NF) ? W1 : W2;
        unsigned short* Wt = (i < NF * NF) ? Wt1 : Wt2;
        int id = i & (NF * NF - 1);
        int f = id >> 7;
        int k = id & 127;
        Wt[f * NF + k] = f2bf(W[k * NF + f]);
    }
    for (int i = gtid; i < NGRAPHS * NF; i += nthreads) sums[i] = 0.f;

    // ---- split ----
    int tile0 = blockIdx.x * SPLIT_TILE;
    int cnt = min(SPLIT_TILE, ne - tile0);
    if (cnt <= 0) return;
    hcnt[t] = 0;
    __syncthreads();
    // pass 1: load (dst,src) into registers + histogram
    int dv[16], sv[16];
#pragma unroll
    for (int k2 = 0; k2 < 16; ++k2) {
        int i = k2 * 256 + t;
        if (i < cnt) {
            dv[k2] = dst[tile0 + i];
            sv[k2] = src[tile0 + i];
            atomicAdd(&hcnt[dv[k2] >> PART_SHIFT], 1);
        }
    }
    __syncthreads();
    // inclusive Hillis-Steele scan of 256 counters
    hscan[t] = hcnt[t];
    __syncthreads();
    for (int off = 1; off < NPARTS; off <<= 1) {
        int v = (t >= off) ? hscan[t - off] : 0;
        __syncthreads();
        hscan[t] += v;
        __syncthreads();
    }
    hcur[t] = hscan[t] - hcnt[t];
    hg[t] = hcnt[t] ? atomicAdd(&gcur[t], hcnt[t]) : 0;
    __syncthreads();
    // pass 2: place packed records from registers
#pragma unroll
    for (int k2 = 0; k2 < 16; ++k2) {
        int i = k2 * 256 + t;
        if (i < cnt) {
            int d = dv[k2];
            int pos = atomicAdd(&hcur[d >> PART_SHIFT], 1);
            stage[pos] = (((unsigned int)(d & (PART_NODES - 1))) << SRC_BITS)
                         | (unsigned int)sv[k2];
        }
    }
    __syncthreads();
    // flush: quarter-wave (16 lanes) per partition, 16 partitions concurrent
    int grp = t >> 4;
    int lt = t & 15;
    for (int p = grp; p < NPARTS; p += 16) {
        int c = hcnt[p];
        if (c == 0) continue;
        int b = hscan[p] - c;
        int g = hg[p];
        if (g + c > PART_CAP) c = max(0, PART_CAP - g);   // never in practice
        unsigned int* outp = records + (size_t)p * PART_CAP + g;
        for (int i = lt; i < c; i += 16) outp[i] = stage[b + i];
    }
}

// ---------------------------------------------------------------------------
// Per-partition CSR build with LDS record cache (r13/r15 configuration).
// ---------------------------------------------------------------------------
__global__ __launch_bounds__(256) void build_kernel(
    const unsigned int* __restrict__ records, const int* __restrict__ gcur,
    int* __restrict__ offs, int* __restrict__ eid, int n) {
    __shared__ int deg[PART_NODES];       // 2 KB; becomes cursor after scan
    __shared__ int ps[NPARTS];            // 1 KB
    __shared__ int wsum[4];
    __shared__ unsigned int rc[PART_CAP]; // 36 KB record cache
    int t = threadIdx.x;
    int p = blockIdx.x;

    // partition-base scan (inclusive)
    ps[t] = min(gcur[t], PART_CAP);
    __syncthreads();
    for (int off = 1; off < NPARTS; off <<= 1) {
        int v = (t >= off) ? ps[t - off] : 0;
        __syncthreads();
        ps[t] += v;
        __syncthreads();
    }
    int L = min(gcur[p], PART_CAP);
    int base_g = ps[p] - L;
    if (p == 0 && t == 0) offs[n] = ps[NPARTS - 1];

    int lo = p << PART_SHIFT;
    int nn = min(n - lo, PART_NODES);
    if (nn <= 0) return;

    deg[t] = 0;
    deg[t + 256] = 0;
    __syncthreads();

    const unsigned int* rp = records + (size_t)p * PART_CAP;
    for (int i = t; i < L; i += 256) {
        unsigned int r = rp[i];
        rc[i] = r;
        atomicAdd(&deg[r >> SRC_BITS], 1);
    }
    __syncthreads();

    // block exclusive scan over deg[0..512) (2 elems/thread)
    int v0 = deg[2 * t];
    int v1 = deg[2 * t + 1];
    int tsum = v0 + v1;
    int lane = t & 63, w = t >> 6;
    int sc = tsum;
    for (int off = 1; off < 64; off <<= 1) {
        int u = __shfl_up(sc, off, 64);
        if (lane >= off) sc += u;
    }
    if (lane == 63) wsum[w] = sc;
    __syncthreads();
    if (t == 0) {
        int a = 0;
        for (int k = 0; k < 4; ++k) { int v = wsum[k]; wsum[k] = a; a += v; }
    }
    __syncthreads();
    int run = sc - tsum + wsum[w];
    deg[2 * t] = run;
    if (2 * t < nn) offs[lo + 2 * t] = base_g + run;
    run += v0;
    deg[2 * t + 1] = run;
    if (2 * t + 1 < nn) offs[lo + 2 * t + 1] = base_g + run;
    __syncthreads();

    // fill eid from the LDS cache
    for (int i = t; i < L; i += 256) {
        unsigned int r = rc[i];
        int pos = atomicAdd(&deg[r >> SRC_BITS], 1);
        eid[base_g + pos] = (int)(r & ((1u << SRC_BITS) - 1));
    }
}

// ---------------------------------------------------------------------------
// Fused gather + MFMA GEMM (layer 1): at the random-256B gather ceiling
// (FETCH = 8 XCDs x ~86.5K unique rows x 256 B compulsory misses).
// ---------------------------------------------------------------------------
__global__ __launch_bounds__(256) void gather_gemm1(
    const unsigned short* __restrict__ x, const int* __restrict__ offs,
    const int* __restrict__ eid, const unsigned short* __restrict__ Wt,
    const float* __restrict__ bias, unsigned short* __restrict__ out, int n) {
    __shared__ unsigned short As[16 * AS_STRIDE];
    int wave = threadIdx.x >> 6;
    int lane = threadIdx.x & 63;
    int q = lane >> 4;        // quarter 0..3
    int c = lane & 15;        // 16B chunk / m-index
    int node_base = blockIdx.x * 16;

    for (int i = 0; i < 4; ++i) {
        int row = wave * 4 + i;
        int node = node_base + row;
        float acc[8] = {0.f, 0.f, 0.f, 0.f, 0.f, 0.f, 0.f, 0.f};
        if (node < n) {
            int beg = offs[node];
            int end = offs[node + 1];
            int j = beg + q;
            for (; j + 4 < end; j += 8) {
                int s0 = eid[j];
                int s1 = eid[j + 4];
                u16x8 v0 = ((const u16x8*)(x + (size_t)s0 * NF))[c];
                u16x8 v1 = ((const u16x8*)(x + (size_t)s1 * NF))[c];
#pragma unroll
                for (int r = 0; r < 8; ++r) acc[r] += bf2f(v0[r]) + bf2f(v1[r]);
            }
            if (j < end) {
                int s0 = eid[j];
                u16x8 v0 = ((const u16x8*)(x + (size_t)s0 * NF))[c];
#pragma unroll
                for (int r = 0; r < 8; ++r) acc[r] += bf2f(v0[r]);
            }
        }
#pragma unroll
        for (int r = 0; r < 8; ++r) acc[r] += __shfl_xor(acc[r], 16, 64);
#pragma unroll
        for (int r = 0; r < 8; ++r) acc[r] += __shfl_xor(acc[r], 32, 64);
        if (q == 0) {
            u16x8 o;
#pragma unroll
            for (int r = 0; r < 8; ++r) o[r] = f2bf(acc[r]);
            *(u16x8*)(&As[row * AS_STRIDE + c * 8]) = o;
        }
    }
    __syncthreads();

    int m16 = c;
    int n0 = wave * 32;
    const unsigned short* b0r = Wt + (size_t)(n0 + m16) * NF + q * 8;
    const unsigned short* b1r = b0r + 16 * NF;
    f32x4 acc0 = {0.f, 0.f, 0.f, 0.f};
    f32x4 acc1 = {0.f, 0.f, 0.f, 0.f};
#pragma unroll
    for (int kk = 0; kk < 4; ++kk) {
        bf16x8 a  = *(const bf16x8*)(&As[m16 * AS_STRIDE + kk * 32 + q * 8]);
        bf16x8 b0 = *(const bf16x8*)(b0r + kk * 32);
        bf16x8 b1 = *(const bf16x8*)(b1r + kk * 32);
        acc0 = __builtin_amdgcn_mfma_f32_16x16x32_bf16(a, b0, acc0, 0, 0, 0);
        acc1 = __builtin_amdgcn_mfma_f32_16x16x32_bf16(a, b1, acc1, 0, 0, 0);
    }
    float bias0 = bias[n0 + m16];
    float bias1 = bias[n0 + 16 + m16];
#pragma unroll
    for (int r = 0; r < 4; ++r) {
        int node = node_base + q * 4 + r;
        if (node >= n) break;
        unsigned short* o = out + (size_t)node * NF;
        o[n0 + m16]      = f2bf(fmaxf(acc0[r] + bias0, 0.f));
        o[n0 + 16 + m16] = f2bf(fmaxf(acc1[r] + bias1, 0.f));
    }
}

// ---------------------------------------------------------------------------
// Fused gather + MFMA GEMM (layer 2) + pool epilogue. No device fences
// (r12 post-mortem: per-block __threadfence = 8x regression).
// ---------------------------------------------------------------------------
__global__ __launch_bounds__(256) void gather_gemm2_pool(
    const unsigned short* __restrict__ x, const int* __restrict__ offs,
    const int* __restrict__ eid, const unsigned short* __restrict__ Wt,
    const float* __restrict__ bias, const int* __restrict__ gid,
    float* __restrict__ sums, int n) {
    __shared__ unsigned short As[16 * AS_STRIDE];
    __shared__ float hblk[16][NF];
    int wave = threadIdx.x >> 6;
    int lane = threadIdx.x & 63;
    int q = lane >> 4;
    int c = lane & 15;
    int node_base = blockIdx.x * 16;

    for (int i = 0; i < 4; ++i) {
        int row = wave * 4 + i;
        int node = node_base + row;
        float acc[8] = {0.f, 0.f, 0.f, 0.f, 0.f, 0.f, 0.f, 0.f};
        if (node < n) {
            int beg = offs[node];
            int end = offs[node + 1];
            int j = beg + q;
            for (; j + 4 < end; j += 8) {
                int s0 = eid[j];
                int s1 = eid[j + 4];
                u16x8 v0 = ((const u16x8*)(x + (size_t)s0 * NF))[c];
                u16x8 v1 = ((const u16x8*)(x + (size_t)s1 * NF))[c];
#pragma unroll
                for (int r = 0; r < 8; ++r) acc[r] += bf2f(v0[r]) + bf2f(v1[r]);
            }
            if (j < end) {
                int s0 = eid[j];
                u16x8 v0 = ((const u16x8*)(x + (size_t)s0 * NF))[c];
#pragma unroll
                for (int r = 0; r < 8; ++r) acc[r] += bf2f(v0[r]);
            }
        }
#pragma unroll
        for (int r = 0; r < 8; ++r) acc[r] += __shfl_xor(acc[r], 16, 64);
#pragma unroll
        for (int r = 0; r < 8; ++r) acc[r] += __shfl_xor(acc[r], 32, 64);
        if (q == 0) {
            u16x8 o;
#pragma unroll
            for (int r = 0; r < 8; ++r) o[r] = f2bf(acc[r]);
            *(u16x8*)(&As[row * AS_STRIDE + c * 8]) = o;
        }
    }
    __syncthreads();

    int m16 = c;
    int n0 = wave * 32;
    const unsigned short* b0r = Wt + (size_t)(n0 + m16) * NF + q * 8;
    const unsigned short* b1r = b0r + 16 * NF;
    f32x4 acc0 = {0.f, 0.f, 0.f, 0.f};
    f32x4 acc1 = {0.f, 0.f, 0.f, 0.f};
#pragma unroll
    for (int kk = 0; kk < 4; ++kk) {
        bf16x8 a  = *(const bf16x8*)(&As[m16 * AS_STRIDE + kk * 32 + q * 8]);
        bf16x8 b0 = *(const bf16x8*)(b0r + kk * 32);
        bf16x8 b1 = *(const bf16x8*)(b1r + kk * 32);
        acc0 = __builtin_amdgcn_mfma_f32_16x16x32_bf16(a, b0, acc0, 0, 0, 0);
        acc1 = __builtin_amdgcn_mfma_f32_16x16x32_bf16(a, b1, acc1, 0, 0, 0);
    }
    float bias0 = bias[n0 + m16];
    float bias1 = bias[n0 + 16 + m16];
#pragma unroll
    for (int r = 0; r < 4; ++r) {
        int row = q * 4 + r;
        hblk[row][n0 + m16]      = fmaxf(acc0[r] + bias0, 0.f);
        hblk[row][n0 + 16 + m16] = fmaxf(acc1[r] + bias1, 0.f);
    }
    __syncthreads();

    int t = threadIdx.x;
    if (t < NF) {
        float acc = 0.f;
        int cur = -1;
        int lim = min(16, n - node_base);
        for (int i = 0; i < lim; ++i) {
            int g = gid[node_base + i];
            if (g != cur) {
                if (cur >= 0) atomicAdd(&sums[cur * NF + t], acc);
                acc = 0.f;
                cur = g;
            }
            acc += bf2f(f2bf(hblk[i][t]));    // keep bf16 rounding of h2 path
        }
        if (cur >= 0) atomicAdd(&sums[cur * NF + t], acc);
    }
}

__device__ __forceinline__ int lower_bound_i(const int* a, int n, int key) {
    int lo = 0, hi = n;
    while (lo < hi) {
        int mid = (lo + hi) >> 1;
        if (a[mid] < key) lo = mid + 1; else hi = mid;
    }
    return lo;
}

__global__ __launch_bounds__(64) void final_kernel(
    const float* __restrict__ sums, const int* __restrict__ gid, int n,
    const float* __restrict__ Wp, const float* __restrict__ bp,
    float* __restrict__ out) {
    __shared__ int range[2];
    int g = blockIdx.x;
    int c = threadIdx.x;
    if (c == 0) range[0] = lower_bound_i(gid, n, g);
    if (c == 1) range[1] = lower_bound_i(gid, n, g + 1);
    __syncthreads();
    if (c >= NCLS) return;
    float cnt = fmaxf((float)(range[1] - range[0]), 1.0f);
    float inv = 1.0f / cnt;
    float acc = bp[c];
#pragma unroll 8
    for (int k = 0; k < NF; ++k) {
        acc += sums[g * NF + k] * inv * Wp[k * NCLS + c];
    }
    out[g * NCLS + c] = acc;
}

extern "C" void kernel_launch(void* const* d_in, const int* in_sizes, int n_in,
                              void* d_out, int out_size, void* d_ws, size_t ws_size,
                              hipStream_t stream) {
    const float* feat = (const float*)d_in[0];
    const float* W1   = (const float*)d_in[1];
    const float* b1   = (const float*)d_in[2];
    const float* W2   = (const float*)d_in[3];
    const float* b2   = (const float*)d_in[4];
    const float* Wp   = (const float*)d_in[5];
    const float* bp   = (const float*)d_in[6];
    const int*   src  = (const int*)d_in[7];
    const int*   dst  = (const int*)d_in[8];
    const int*   gid  = (const int*)d_in[9];

    int ne = in_sizes[7];
    int n  = in_sizes[9];

    // Workspace (16B-aligned segments):
    unsigned short* featbf = (unsigned short*)d_ws;                  // n*128 u16
    unsigned short* h1     = featbf + (size_t)n * NF;                // n*128 u16
    unsigned int* records = (unsigned int*)(h1 + (size_t)n * NF);    // 256*PART_CAP u32
    int* eid      = (int*)(records + (size_t)NPARTS * PART_CAP);     // ne
    float* sums   = (float*)(eid + ne);                              // 64*128
    int* gcur     = (int*)(sums + NGRAPHS * NF);                     // 256
    unsigned short* Wt1 = (unsigned short*)(gcur + NPARTS);          // 128*128
    unsigned short* Wt2 = Wt1 + NF * NF;                             // 128*128
    int* offs     = (int*)(Wt2 + NF * NF);                           // n+1

    int nv4 = n * NF / 4;
    int splitblocks = (ne + SPLIT_TILE - 1) / SPLIT_TILE;
    int buildblocks = (n + PART_NODES - 1) >> PART_SHIFT;
    int ggblocks = (n + 15) / 16;

    hipMemsetAsync(gcur, 0, NPARTS * sizeof(int), stream);
    split_prep_kernel<<<splitblocks, 256, 0, stream>>>(
        src, dst, records, gcur, feat, featbf, W1, W2, Wt1, Wt2, sums, ne, nv4);
    build_kernel<<<buildblocks, 256, 0, stream>>>(records, gcur, offs, eid, n);

    gather_gemm1<<<ggblocks, 256, 0, stream>>>(featbf, offs, eid, Wt1, b1, h1, n);
    gather_gemm2_pool<<<ggblocks, 256, 0, stream>>>(h1, offs, eid, Wt2, b2, gid, sums, n);
    final_kernel<<<NGRAPHS, 64, 0, stream>>>(sums, gid, n, Wp, bp, (float*)d_out);
}